// Round 18
// baseline (268.211 us; speedup 1.0000x reference)
//
#include <hip/hip_runtime.h>
#include <stdint.h>

typedef __bf16 bf16x8 __attribute__((ext_vector_type(8)));
typedef float f32x4 __attribute__((ext_vector_type(4)));

constexpr int NB = 8;      // batch
constexpr int NC = 256;    // channels C
constexpr int NN = 2048;   // sequence N
constexpr int NH = 4;      // heads
constexpr int ND = 64;     // head dim
constexpr int NC2 = 512;   // 2C
constexpr size_t TND = (size_t)NB * NN * NC;
// exp(x*0.125) == exp2(x * C2)
__device__ constexpr float C2 = 0.125f * 1.4426950408889634f;

__device__ __forceinline__ ushort f2bf(float f) {
  union { float f; uint32_t u; } x; x.f = f;
  return (ushort)((x.u + 0x7FFFu + ((x.u >> 16) & 1u)) >> 16);
}
__device__ __forceinline__ float bf2f(ushort h) {
  union { uint32_t u; float f; } x; x.u = (uint32_t)h << 16;
  return x.f;
}

// LDS-only barrier: drain ds ops, sync — but leave global loads/stores in
// flight (no vmcnt(0) drain, unlike __syncthreads). T4 pattern.
__device__ __forceinline__ void bar_lds() {
  __builtin_amdgcn_sched_barrier(0);
  asm volatile("s_waitcnt lgkmcnt(0)" ::: "memory");
  __builtin_amdgcn_s_barrier();
  __builtin_amdgcn_sched_barrier(0);
}

// ---------------- merged weight-cast kernel ----------------
// (r15 lesson: do NOT inline these casts into the GEMMs — the stride-4 Wm
// gather and f32 weight re-staging cost ~50us; this coalesced pass is ~10us.)

__global__ void k_cast_all(const float* __restrict__ Wq, const float* __restrict__ Wk,
                           const float* __restrict__ Wv, const float* __restrict__ Wm,
                           const float* __restrict__ W1, const float* __restrict__ W2,
                           ushort* __restrict__ wqkv, ushort* __restrict__ wm_b,
                           ushort* __restrict__ w1_b, ushort* __restrict__ w2_b) {
  int i = blockIdx.x * 256 + threadIdx.x;
  if (i < 196608) {
    int op = i >> 16, j = i & 65535;
    int r = j >> 8, c = j & 255;
    const float* s = op == 0 ? Wq : op == 1 ? Wk : Wv;
    int orig = op < 2 ? (((r & 63) << 2) | (r >> 6)) : r;
    wqkv[i] = f2bf(s[orig * NC + c]);
  } else if (i < 262144) {
    int j = i - 196608;
    int co = j >> 8, jj = j & 255;
    wm_b[j] = f2bf(Wm[co * NC + (jj & 63) * NH + (jj >> 6)]);
  } else if (i < 524288) {
    int j = i - 262144;
    w1_b[j] = f2bf(W1[j]);
  } else {
    int j = i - 524288;
    w2_b[j] = f2bf(W2[j]);
  }
}

// ---------------- fused flash attention (128-row strip, 8 waves) ----------------
// 512 blocks = 8 XCD x 4 bh x 16 q-strips of 128 rows; 512 thr = 8 waves,
// wave w owns q-rows [w*16, w*16+16). LDS = 48 KB total (2-block residency):
// KV[4][4096] — pass 1 uses all four as a 2x2 double-buffered-pair K pipeline
// (128 cols / barrier -> 16 barriers); pass 2 reuses as Kl[2]+Vl[2] (KVBLK=64,
// 32 barriers, barrier also guards the P tile). Pass 1 sums exp2 directly
// (scores bounded, no max tracking); normalizer mC = log2(sum).

__device__ __forceinline__ bf16x8 ldtile(const ushort* base, int lr, int lg, int fc, int ks) {
  int row = fc * 16 + lr;
  int u = (ks * 4 + lg) ^ (lr & 7);
  return *(const bf16x8*)((const char*)base + row * 128 + u * 16);
}

__global__ __launch_bounds__(512, 4) void k_attn(
    const ushort* __restrict__ qt, const ushort* __restrict__ kt,
    const ushort* __restrict__ vnat, float* __restrict__ attn,
    ushort* __restrict__ xT) {
  __shared__ ushort KV[4][4096];   // 32 KB, swizzled: unit ^= row&7
  __shared__ ushort Pl[8192];      // 128x64 bf16, byte ^= (row&7)<<4

  const int tid = threadIdx.x;
  const int lane = tid & 63, w = tid >> 6;      // 8 waves
  const int lr = lane & 15, lg = lane >> 4;

  int flat = blockIdx.x;
  int xcd = flat & 7, idx = flat >> 3;          // idx 0..63
  int z = xcd * 4 + (idx >> 4);                 // 4 bh per XCD -> K/V L2-resident
  int r0 = (idx & 15) * 128;
  int b = z >> 2, h = z & 3;

  const ushort* kbase = kt + (size_t)z * NN * ND;
  const ushort* vbase = vnat + ((size_t)b * NC + h) * NN;

  // staging geometry: 512 segments of 16B, one per thread per 64-row subtile
  const int sr0 = tid >> 3, sc0 = tid & 7;
  const int d0 = sr0 * 128 + ((sc0 ^ (sr0 & 7)) << 4);

  // Q fragments (coalesced from qt [z][n][d])
  bf16x8 aq0, aq1;
  {
    const ushort* qp = qt + ((size_t)z * NN + r0 + w * 16 + lr) * ND;
    aq0 = *(const bf16x8*)(qp + lg * 8);
    aq1 = *(const bf16x8*)(qp + 32 + lg * 8);
  }

  uint4 gk[2], gv0;

  // ---- pass 1 prologue: stage K cols 0..127 (subtiles 0,1), issue 128..255 ----
  gk[0] = *(const uint4*)(kbase + (size_t)sr0 * ND + sc0 * 8);
  gk[1] = *(const uint4*)(kbase + (size_t)(64 + sr0) * ND + sc0 * 8);
  *(uint4*)((char*)KV[0] + d0) = gk[0];
  *(uint4*)((char*)KV[1] + d0) = gk[1];
  gk[0] = *(const uint4*)(kbase + (size_t)(128 + sr0) * ND + sc0 * 8);
  gk[1] = *(const uint4*)(kbase + (size_t)(192 + sr0) * ND + sc0 * 8);
  bar_lds();

  float s_ln[4];
#pragma unroll
  for (int j = 0; j < 4; ++j) s_ln[j] = 0.f;

  // ---- pass 1: direct exp2 row sums; one barrier per 128 cols (16 total) ----
  for (int t = 0; t < 16; ++t) {
    int base = (t & 1) * 2;
    if (t < 15) {
      *(uint4*)((char*)KV[base ^ 2] + d0) = gk[0];
      *(uint4*)((char*)KV[(base ^ 2) + 1] + d0) = gk[1];
    }
    if (t < 14) {
      gk[0] = *(const uint4*)(kbase + ((size_t)(t + 2) * 128 + sr0) * ND + sc0 * 8);
      gk[1] = *(const uint4*)(kbase + ((size_t)(t + 2) * 128 + 64 + sr0) * ND + sc0 * 8);
    }
#pragma unroll
    for (int s = 0; s < 2; ++s) {
      f32x4 sa[4] = {};
#pragma unroll
      for (int ks = 0; ks < 2; ++ks) {
        bf16x8 aqk = ks ? aq1 : aq0;
#pragma unroll
        for (int fc = 0; fc < 4; ++fc)
          sa[fc] = __builtin_amdgcn_mfma_f32_16x16x32_bf16(aqk, ldtile(KV[base + s], lr, lg, fc, ks), sa[fc], 0, 0, 0);
      }
#pragma unroll
      for (int j = 0; j < 4; ++j) {
        s_ln[j] += exp2f(sa[0][j] * C2) + exp2f(sa[1][j] * C2)
                 + exp2f(sa[2][j] * C2) + exp2f(sa[3][j] * C2);
      }
    }
    bar_lds();
  }

  // merge the 16 lane-partials per row; normalizer in log2 domain
  float mC[4];
#pragma unroll
  for (int j = 0; j < 4; ++j) {
    float c = s_ln[j];
#pragma unroll
    for (int o = 1; o < 16; o <<= 1) c += __shfl_xor(c, o);
    mC[j] = __log2f(c);
  }

  // ---- pass 2 prologue: stage K,V tile 0, issue tile 1 (Kl=KV[0..1] as 2 bufs? no:
  // Kl buffers are KV[0],KV[1]; Vl buffers KV[2],KV[3]) ----
  gk[0] = *(const uint4*)(kbase + (size_t)sr0 * ND + sc0 * 8);
  gv0 = *(const uint4*)(vbase + (size_t)sr0 * 4 * NN + sc0 * 8);
  *(uint4*)((char*)KV[0] + d0) = gk[0];
  *(uint4*)((char*)KV[2] + d0) = gv0;
  gk[0] = *(const uint4*)(kbase + (size_t)(64 + sr0) * ND + sc0 * 8);
  gv0 = *(const uint4*)(vbase + (size_t)sr0 * 4 * NN + 64 + sc0 * 8);
  bar_lds();

  // ---- pass 2: recompute S, write attn once, PV; one barrier per tile ----
  f32x4 acc[4] = {};
  const int prow = w * 16 + lr;
  char* plb = (char*)Pl;
  for (int t = 0; t < 32; ++t) {
    int kb = t & 1;
    if (t < 31) {
      *(uint4*)((char*)KV[kb ^ 1] + d0) = gk[0];
      *(uint4*)((char*)KV[2 + (kb ^ 1)] + d0) = gv0;
    }
    if (t < 30) {
      gk[0] = *(const uint4*)(kbase + ((size_t)(t + 2) * 64 + sr0) * ND + sc0 * 8);
      gv0 = *(const uint4*)(vbase + (size_t)sr0 * 4 * NN + (t + 2) * 64 + sc0 * 8);
    }
    f32x4 sa[4] = {};
#pragma unroll
    for (int ks = 0; ks < 2; ++ks) {
      bf16x8 aqk = ks ? aq1 : aq0;
#pragma unroll
      for (int fc = 0; fc < 4; ++fc)
        sa[fc] = __builtin_amdgcn_mfma_f32_16x16x32_bf16(aqk, ldtile(KV[kb], lr, lg, fc, ks), sa[fc], 0, 0, 0);
    }
    // normalized P -> LDS (bf16, swizzled); norm folded into exponent
#pragma unroll
    for (int fc = 0; fc < 4; ++fc)
#pragma unroll
      for (int j = 0; j < 4; ++j) {
        int row = w * 16 + lg * 4 + j;
        float p = exp2f(fmaf(sa[fc][j], C2, -mC[j]));
        int byte = (row << 7) + ((fc * 16 + lr) << 1);
        byte ^= (row & 7) << 4;
        *(ushort*)(plb + byte) = f2bf(p);
      }
    // attn store: vectorized f32x4 NT from the LDS P tile (wave-local slab)
    float* abase = attn + ((size_t)z * NN + r0) * NN + t * 64;
#pragma unroll
    for (int k = 0; k < 4; ++k) {
      int row = w * 16 + lg + k * 4;
      int byte = (row << 7) + (lr << 3);
      byte ^= (row & 7) << 4;
      const ushort* pq = (const ushort*)(plb + byte);
      f32x4 vv = { bf2f(pq[0]), bf2f(pq[1]), bf2f(pq[2]), bf2f(pq[3]) };
      __builtin_nontemporal_store(vv, (f32x4*)(abase + (size_t)row * NN + lr * 4));
    }
    // PV MFMA from LDS P and V
#pragma unroll
    for (int ks = 0; ks < 2; ++ks) {
      int abyte = (prow << 7) + ks * 64 + lg * 16;
      abyte ^= (prow & 7) << 4;
      bf16x8 ap = *(const bf16x8*)(plb + abyte);
#pragma unroll
      for (int fc = 0; fc < 4; ++fc)
        acc[fc] = __builtin_amdgcn_mfma_f32_16x16x32_bf16(ap, ldtile(KV[2 + kb], lr, lg, fc, ks), acc[fc], 0, 0, 0);
    }
    bar_lds();
  }
  // epilogue: xT[b][n][h*64+d]
#pragma unroll
  for (int fc = 0; fc < 4; ++fc)
#pragma unroll
    for (int j = 0; j < 4; ++j) {
      int n = r0 + w * 16 + lg * 4 + j;
      xT[((size_t)b * NN + n) * NC + h * 64 + fc * 16 + lr] = f2bf(acc[fc][j]);
    }
}

// ---------------- generic MFMA GEMM: D[r][c] = sum_k A[r][k]*B[c][k] ----------------

enum GemmMode { M_PROJ = 0, M_WM, M_W1, M_W2 };

template <int MODE>
__global__ __launch_bounds__(256) void k_gemm(
    const ushort* __restrict__ A, const ushort* __restrict__ Bm,
    const float* __restrict__ Fa, const float* __restrict__ Fb, const float* __restrict__ Fc,
    const float* __restrict__ b0, const float* __restrict__ b1v, const float* __restrict__ b2v,
    const float* __restrict__ gamma, const float* __restrict__ beta,
    float* __restrict__ stats,
    float* __restrict__ outf, ushort* __restrict__ outb, ushort* __restrict__ outb2) {
  constexpr int BR = (MODE == M_WM || MODE == M_W1) ? 64 : 128;
  constexpr int BC = (MODE == M_W1) ? 256 : (MODE == M_W2) ? 64 : 128;
  constexpr int KT = (MODE == M_PROJ || MODE == M_WM) ? 256 : 512;
  constexpr int FR = BR / 32;
  constexpr int FC = BC / 32;
  constexpr int LDL = 72;

  __shared__ ushort ldsU[BR * LDL + BC * LDL];
  __shared__ float4 affl[(MODE == M_W2) ? NC2 : 1];
  ushort* ldsA = ldsU;
  ushort* ldsB = ldsU + BR * LDL;

  const int tid = threadIdx.x;
  const int lane = tid & 63, wave = tid >> 6;
  const int wr = (wave >> 1) * (FR * 16), wc = (wave & 1) * (FC * 16);
  const int lr = lane & 15, lg = lane >> 4, lk = lg * 8;
  const int c0 = blockIdx.x * BC, r0 = blockIdx.y * BR;
  const int op = (MODE == M_PROJ) ? (int)(blockIdx.z >> 3) : 0;
  const size_t z = (MODE == M_PROJ) ? (blockIdx.z & 7) : blockIdx.z;

  // M_W2: build BN affine table in LDS from stats (deletes k_bn_finalize launch)
  if constexpr (MODE == M_W2) {
    const float inv_n = 1.f / (float)(NB * NN);
    for (int c = tid; c < NC2; c += 256) {
      float mu  = stats[c * 2] * inv_n;
      float var = stats[c * 2 + 1] * inv_n - mu * mu;
      float isg = gamma[c] * rsqrtf(var + 1e-5f);
      affl[c] = make_float4(mu, isg, beta[c], 0.f);
    }
    __syncthreads();
  }

  // stage [ROWS rows][64 k] bf16 tile from f32 src laid out [k][row] (stride NN)
  auto stage_t = [&](ushort* dst, const float* src, int ROWS) {
    int n = tid & (ROWS - 1), cgb = tid / ROWS;
    int gpp = 256 / ROWS;
    for (int u = 0; u < 8 / gpp; ++u) {
      int cg = cgb + u * gpp;
      union { ushort us[8]; uint4 v; } pk;
#pragma unroll
      for (int e = 0; e < 8; ++e)
        pk.us[e] = f2bf(src[(size_t)(cg * 8 + e) * NN + n]);
      *(uint4*)&dst[n * LDL + cg * 8] = pk.v;
    }
  };

  f32x4 acc[FR][FC] = {};

  for (int kk = 0; kk < KT; kk += 64) {
    // ---- stage A ----
    if constexpr (MODE == M_W1) {
      if (kk < NC) {
        const ushort* src = A + (z * NN + r0) * (size_t)NC + kk;
#pragma unroll
        for (int i = 0; i < BR / 32; ++i) {
          int off = (tid + i * 256) * 8, row = off >> 6, k = off & 63;
          *(uint4*)&ldsA[row * LDL + k] = *(const uint4*)(src + (size_t)row * NC + k);
        }
      } else {
        stage_t(ldsA, Fa + ((size_t)z * NC + (kk - NC)) * NN + r0, BR);
      }
    } else {
      const ushort* src; int ld;
      if constexpr (MODE == M_PROJ)        { src = A + (size_t)op * NC * NC + (size_t)r0 * NC + kk; ld = NC; }
      else if constexpr (MODE == M_WM)     { src = A + (z * NN + r0) * (size_t)NC + kk; ld = NC; }
      else                                  { src = A + (size_t)r0 * NC2 + kk; ld = NC2; }   // M_W2
#pragma unroll
      for (int i = 0; i < BR / 32; ++i) {
        int off = (tid + i * 256) * 8, row = off >> 6, k = off & 63;
        *(uint4*)&ldsA[row * LDL + k] = *(const uint4*)(src + (size_t)row * ld + k);
      }
    }
    // ---- stage B ----
    if constexpr (MODE == M_PROJ) {
      const float* Fsel = op == 0 ? Fa : op == 1 ? Fb : Fc;
      stage_t(ldsB, Fsel + ((size_t)z * NC + kk) * NN + c0, BC);
    } else if constexpr (MODE == M_W2) {
      const ushort* src = Bm + (z * NN + c0) * (size_t)NC2 + kk;
#pragma unroll
      for (int i = 0; i < BC / 32; ++i) {
        int off = (tid + i * 256) * 8, row = off >> 6, k = off & 63;
        union { ushort u[8]; uint4 v; } t, o;
        t.v = *(const uint4*)(src + (size_t)row * NC2 + k);
#pragma unroll
        for (int e = 0; e < 8; ++e) {
          float4 pr = affl[kk + k + e];
          float y = (bf2f(t.u[e]) - pr.x) * pr.y + pr.z;
          y = y > 0.f ? y : 0.2f * y;
          o.u[e] = f2bf(y);
        }
        *(uint4*)&ldsB[row * LDL + k] = o.v;
      }
    } else {
      const ushort* src; int ld;
      if constexpr (MODE == M_WM)          { src = Bm + (size_t)c0 * NC + kk; ld = NC; }
      else                                  { src = Bm + (size_t)c0 * NC2 + kk; ld = NC2; }  // M_W1
#pragma unroll
      for (int i = 0; i < BC / 32; ++i) {
        int off = (tid + i * 256) * 8, row = off >> 6, k = off & 63;
        *(uint4*)&ldsB[row * LDL + k] = *(const uint4*)(src + (size_t)row * ld + k);
      }
    }
    __syncthreads();
#pragma unroll
    for (int ks = 0; ks < 2; ++ks) {
      bf16x8 afr[FR], bfr[FC];
#pragma unroll
      for (int fr = 0; fr < FR; ++fr)
        afr[fr] = *(const bf16x8*)&ldsA[(wr + fr * 16 + lr) * LDL + ks * 32 + lk];
#pragma unroll
      for (int fc = 0; fc < FC; ++fc)
        bfr[fc] = *(const bf16x8*)&ldsB[(wc + fc * 16 + lr) * LDL + ks * 32 + lk];
#pragma unroll
      for (int fr = 0; fr < FR; ++fr)
#pragma unroll
        for (int fc = 0; fc < FC; ++fc)
          acc[fr][fc] = __builtin_amdgcn_mfma_f32_16x16x32_bf16(afr[fr], bfr[fc], acc[fr][fc], 0, 0, 0);
    }
    __syncthreads();
  }

  // ---- epilogues ----
  if constexpr (MODE == M_PROJ) {
    if (op < 2) {
      // transpose via LDS (reuse staging space), coalesced write to qt/kt [z][n][d]
      const float* bb = op == 0 ? b0 : b1v;
      char* tb = (char*)ldsU;
#pragma unroll
      for (int fr = 0; fr < FR; ++fr)
#pragma unroll
        for (int fc = 0; fc < FC; ++fc) {
          int n_l = wc + fc * 16 + lr;
          int rb = wr + fr * 16 + lg * 4;
          union { ushort u[4]; uint2 v; } pk;
#pragma unroll
          for (int j = 0; j < 4; ++j) {
            int r = r0 + rb + j;
            pk.u[j] = f2bf(acc[fr][fc][j] + bb[((r & 63) << 2) | (r >> 6)]);
          }
          int byte = n_l * 256 + rb * 2;
          byte ^= (n_l & 7) << 4;
          *(uint2*)(tb + byte) = pk.v;
        }
      __syncthreads();
      ushort* dst = outb + (size_t)op * TND;
#pragma unroll
      for (int hh = 0; hh < 2; ++hh) {
        size_t zz = z * 4 + (r0 >> 6) + hh;
#pragma unroll
        for (int u = 0; u < 4; ++u) {
          int seg = u * 256 + tid;
          int n_l = seg >> 3, dd = (seg & 7) * 8;
          int byte = n_l * 256 + (hh * 64 + dd) * 2;
          byte ^= (n_l & 7) << 4;
          uint4 v = *(const uint4*)(tb + byte);
          *(uint4*)(dst + (zz * NN + c0 + n_l) * (size_t)ND + dd) = v;
        }
      }
    } else {
#pragma unroll
      for (int fr = 0; fr < FR; ++fr)
#pragma unroll
        for (int fc = 0; fc < FC; ++fc)
#pragma unroll
          for (int j = 0; j < 4; ++j) {
            int r = r0 + wr + fr * 16 + lg * 4 + j;
            int c = c0 + wc + fc * 16 + lr;
            outb2[(z * NC + r) * (size_t)NN + c] = f2bf(acc[fr][fc][j] + b2v[r]);
          }
    }
    return;
  }

  float sfc[FC], qfc[FC];
#pragma unroll
  for (int fc = 0; fc < FC; ++fc) { sfc[fc] = 0.f; qfc[fc] = 0.f; }
#pragma unroll
  for (int fr = 0; fr < FR; ++fr)
#pragma unroll
    for (int fc = 0; fc < FC; ++fc)
#pragma unroll
      for (int j = 0; j < 4; ++j) {
        int r = r0 + wr + fr * 16 + lg * 4 + j;
        int c = c0 + wc + fc * 16 + lr;
        float v = acc[fr][fc][j];
        if constexpr (MODE == M_WM) {
          v += b0[c];
          outb[(z * NN + r) * (size_t)NC + c] = f2bf(v);
        } else if constexpr (MODE == M_W1) {
          v += b0[c];
          outb[(z * NN + r) * (size_t)NC2 + c] = f2bf(v);
          sfc[fc] += v; qfc[fc] += v * v;
        } else {  // M_W2
          v += b0[r];
          outf[(z * NC + r) * (size_t)NN + c] = v;
        }
      }
  if constexpr (MODE == M_W1) {
#pragma unroll
    for (int fc = 0; fc < FC; ++fc) {
      float s1 = sfc[fc], s2 = qfc[fc];
      s1 += __shfl_xor(s1, 16); s1 += __shfl_xor(s1, 32);
      s2 += __shfl_xor(s2, 16); s2 += __shfl_xor(s2, 32);
      if (lane < 16) {
        int ch = c0 + wc + fc * 16 + lane;
        atomicAdd(&stats[ch * 2],     s1);
        atomicAdd(&stats[ch * 2 + 1], s2);
      }
    }
  }
}

// ---------------- launch ----------------

extern "C" void kernel_launch(void* const* d_in, const int* in_sizes, int n_in,
                              void* d_out, int out_size, void* d_ws, size_t ws_size,
                              hipStream_t stream) {
  const float* iq    = (const float*)d_in[0];
  const float* keyi  = (const float*)d_in[1];
  const float* vali  = (const float*)d_in[2];
  const float* Wq = (const float*)d_in[3];  const float* bq = (const float*)d_in[4];
  const float* Wk = (const float*)d_in[5];  const float* bk = (const float*)d_in[6];
  const float* Wv = (const float*)d_in[7];  const float* bv = (const float*)d_in[8];
  const float* Wm = (const float*)d_in[9];  const float* bm = (const float*)d_in[10];
  const float* W1 = (const float*)d_in[11]; const float* b1 = (const float*)d_in[12];
  const float* gamma = (const float*)d_in[13]; const float* beta = (const float*)d_in[14];
  const float* W2 = (const float*)d_in[15]; const float* b2 = (const float*)d_in[16];

  float* out  = (float*)d_out;
  float* attn = out + (size_t)NB * NC * NN;   // [B,H,N,N] f32

  uint8_t* cur = (uint8_t*)d_ws;
  auto alloc = [&](size_t bytes) { uint8_t* p = cur; cur += (bytes + 255) & ~(size_t)255; return p; };
  ushort* wqkv  = (ushort*)alloc((size_t)NC * NC * 2 * 3);   // q(perm)|k(perm)|v
  ushort* wm_b  = (ushort*)alloc((size_t)NC * NC * 2);
  ushort* w1_b  = (ushort*)alloc((size_t)NC2 * NC2 * 2);
  ushort* w2_b  = (ushort*)alloc((size_t)NC * NC2 * 2);
  ushort* qtkt  = (ushort*)alloc(TND * 2 * 2);  // qt|kt [(b h)][n][d]
  ushort* v_nat = (ushort*)alloc(TND * 2);      // [b][c_out][n]
  ushort* xT    = (ushort*)alloc(TND * 2);      // attn@V, [b][n][h*64+d]
  ushort* xmT   = (ushort*)alloc(TND * 2);      // merge out^T [b][n][co]
  ushort* hT    = (ushort*)alloc((size_t)NB * NN * NC2 * 2);
  float*  stats = (float*)alloc(NC2 * 2 * 4);
  ushort* kt    = qtkt + TND;

  (void)hipMemsetAsync(stats, 0, NC2 * 2 * 4, stream);

  k_cast_all<<<dim3(2560), 256, 0, stream>>>(Wq, Wk, Wv, Wm, W1, W2, wqkv, wm_b, w1_b, w2_b);

  k_gemm<M_PROJ><<<dim3(16, 2, 24), 256, 0, stream>>>(
      wqkv, nullptr, iq, keyi, vali, bq, bk, bv, nullptr, nullptr, nullptr, nullptr, qtkt, v_nat);

  k_attn<<<dim3(512), 512, 0, stream>>>(qtkt, kt, v_nat, attn, xT);

  k_gemm<M_WM><<<dim3(2, 32, 8), 256, 0, stream>>>(
      xT, wm_b, nullptr, nullptr, nullptr, bm, nullptr, nullptr, nullptr, nullptr, nullptr, nullptr, xmT, nullptr);

  k_gemm<M_W1><<<dim3(2, 32, 8), 256, 0, stream>>>(
      xmT, w1_b, iq, nullptr, nullptr, b1, nullptr, nullptr, nullptr, nullptr, stats, nullptr, hT, nullptr);

  k_gemm<M_W2><<<dim3(32, 2, 8), 256, 0, stream>>>(
      w2_b, hT, nullptr, nullptr, nullptr, b2, nullptr, nullptr, gamma, beta, stats, out, nullptr, nullptr);
}

// Round 20
// 258.009 us; speedup vs baseline: 1.0395x; 1.0395x over previous
//
#include <hip/hip_runtime.h>
#include <stdint.h>

typedef __bf16 bf16x8 __attribute__((ext_vector_type(8)));
typedef float f32x4 __attribute__((ext_vector_type(4)));

constexpr int NB = 8;      // batch
constexpr int NC = 256;    // channels C
constexpr int NN = 2048;   // sequence N
constexpr int NH = 4;      // heads
constexpr int ND = 64;     // head dim
constexpr int NC2 = 512;   // 2C
constexpr size_t TND = (size_t)NB * NN * NC;
// exp(x*0.125) == exp2(x * C2)
__device__ constexpr float C2 = 0.125f * 1.4426950408889634f;

__device__ __forceinline__ ushort f2bf(float f) {
  union { float f; uint32_t u; } x; x.f = f;
  return (ushort)((x.u + 0x7FFFu + ((x.u >> 16) & 1u)) >> 16);
}
__device__ __forceinline__ float bf2f(ushort h) {
  union { uint32_t u; float f; } x; x.u = (uint32_t)h << 16;
  return x.f;
}

// LDS-only barrier: drain ds ops, sync — but leave global loads/stores in
// flight (no vmcnt(0) drain, unlike __syncthreads). T4 pattern.
__device__ __forceinline__ void bar_lds() {
  __builtin_amdgcn_sched_barrier(0);
  asm volatile("s_waitcnt lgkmcnt(0)" ::: "memory");
  __builtin_amdgcn_s_barrier();
  __builtin_amdgcn_sched_barrier(0);
}

// ---------------- merged weight-cast kernel ----------------

__global__ void k_cast_all(const float* __restrict__ Wq, const float* __restrict__ Wk,
                           const float* __restrict__ Wv, const float* __restrict__ Wm,
                           const float* __restrict__ W1, const float* __restrict__ W2,
                           ushort* __restrict__ wqkv, ushort* __restrict__ wm_b,
                           ushort* __restrict__ w1_b, ushort* __restrict__ w2_b) {
  int i = blockIdx.x * 256 + threadIdx.x;
  if (i < 196608) {
    int op = i >> 16, j = i & 65535;
    int r = j >> 8, c = j & 255;
    const float* s = op == 0 ? Wq : op == 1 ? Wk : Wv;
    int orig = op < 2 ? (((r & 63) << 2) | (r >> 6)) : r;
    wqkv[i] = f2bf(s[orig * NC + c]);
  } else if (i < 262144) {
    int j = i - 196608;
    int co = j >> 8, jj = j & 255;
    wm_b[j] = f2bf(Wm[co * NC + (jj & 63) * NH + (jj >> 6)]);
  } else if (i < 524288) {
    int j = i - 262144;
    w1_b[j] = f2bf(W1[j]);
  } else {
    int j = i - 524288;
    w2_b[j] = f2bf(W2[j]);
  }
}

__global__ void k_bn_finalize(const float* __restrict__ stats, const float* __restrict__ gamma,
                              const float* __restrict__ beta, float4* __restrict__ aff) {
  int c = blockIdx.x * 256 + threadIdx.x;
  if (c >= NC2) return;
  const float inv_n = 1.f / (float)(NB * NN);
  float mu  = stats[c * 2] * inv_n;
  float var = stats[c * 2 + 1] * inv_n - mu * mu;
  float isg = gamma[c] * rsqrtf(var + 1e-5f);
  aff[c] = make_float4(mu, isg, beta[c], 0.f);
}

// ---------------- fused flash attention (128-row strip, 8 waves) ----------------
// 512 blocks = 8 XCD x 4 bh x 16 q-strips of 128 rows; 512 thr = 8 waves,
// wave w owns q-rows [w*16, w*16+16). K/V double-buffered in swizzled LDS
// (one 16B seg per thread per tile); one LDS barrier per tile. attn written
// once via the LDS P tile (4 x f32x4 NT per lane per tile).

__device__ __forceinline__ bf16x8 ldtile(const ushort* base, int lr, int lg, int fc, int ks) {
  int row = fc * 16 + lr;
  int u = (ks * 4 + lg) ^ (lr & 7);
  return *(const bf16x8*)((const char*)base + row * 128 + u * 16);
}

__global__ __launch_bounds__(512, 4) void k_attn(
    const ushort* __restrict__ qt, const ushort* __restrict__ kt,
    const ushort* __restrict__ vnat, float* __restrict__ attn,
    ushort* __restrict__ xT) {
  __shared__ ushort Kl[2][4096];   // 2 x 8 KB, swizzled: unit ^= row&7
  __shared__ ushort Vl[2][4096];
  __shared__ ushort Pl[8192];      // 128x64 bf16, byte ^= (row&7)<<4

  const int tid = threadIdx.x;
  const int lane = tid & 63, w = tid >> 6;      // 8 waves
  const int lr = lane & 15, lg = lane >> 4;

  int flat = blockIdx.x;
  int xcd = flat & 7, idx = flat >> 3;          // idx 0..63
  int z = xcd * 4 + (idx >> 4);                 // 4 bh per XCD -> K/V L2-resident
  int r0 = (idx & 15) * 128;
  int b = z >> 2, h = z & 3;

  const ushort* kbase = kt + (size_t)z * NN * ND;
  const ushort* vbase = vnat + ((size_t)b * NC + h) * NN;

  // staging geometry: 512 segments of 16B, one per thread
  const int sr0 = tid >> 3, sc0 = tid & 7;
  const int d0 = sr0 * 128 + ((sc0 ^ (sr0 & 7)) << 4);

  // Q fragments (coalesced from qt [z][n][d])
  bf16x8 aq0, aq1;
  {
    const ushort* qp = qt + ((size_t)z * NN + r0 + w * 16 + lr) * ND;
    aq0 = *(const bf16x8*)(qp + lg * 8);
    aq1 = *(const bf16x8*)(qp + 32 + lg * 8);
  }

  uint4 gk0, gv0;

  // ---- pass 1 prologue: stage K tile 0, issue tile 1 ----
  gk0 = *(const uint4*)(kbase + (size_t)sr0 * ND + sc0 * 8);
  *(uint4*)((char*)Kl[0] + d0) = gk0;
  gk0 = *(const uint4*)(kbase + (size_t)(64 + sr0) * ND + sc0 * 8);
  bar_lds();

  float m_ln[4], s_ln[4];
#pragma unroll
  for (int j = 0; j < 4; ++j) { m_ln[j] = -INFINITY; s_ln[j] = 0.f; }

  // ---- pass 1: online row max / sum, one LDS barrier per tile ----
  for (int t = 0; t < 32; ++t) {
    int kb = t & 1;
    if (t < 31) *(uint4*)((char*)Kl[kb ^ 1] + d0) = gk0;
    if (t < 30)
      gk0 = *(const uint4*)(kbase + ((size_t)(t + 2) * 64 + sr0) * ND + sc0 * 8);
    f32x4 sa[4] = {};
#pragma unroll
    for (int ks = 0; ks < 2; ++ks) {
      bf16x8 aqk = ks ? aq1 : aq0;
#pragma unroll
      for (int fc = 0; fc < 4; ++fc)
        sa[fc] = __builtin_amdgcn_mfma_f32_16x16x32_bf16(aqk, ldtile(Kl[kb], lr, lg, fc, ks), sa[fc], 0, 0, 0);
    }
#pragma unroll
    for (int j = 0; j < 4; ++j) {
      float tm = fmaxf(fmaxf(sa[0][j], sa[1][j]), fmaxf(sa[2][j], sa[3][j]));
      float mn = fmaxf(m_ln[j], tm);
      float mnC = mn * C2;
      float es = exp2f(fmaf(sa[0][j], C2, -mnC)) + exp2f(fmaf(sa[1][j], C2, -mnC))
               + exp2f(fmaf(sa[2][j], C2, -mnC)) + exp2f(fmaf(sa[3][j], C2, -mnC));
      s_ln[j] = s_ln[j] * exp2f(fmaf(m_ln[j], C2, -mnC)) + es;
      m_ln[j] = mn;
    }
    bar_lds();
  }

  // merge the 16 lane-partials per row; fold norm into the exponent
  float mC[4];
#pragma unroll
  for (int j = 0; j < 4; ++j) {
    float m = m_ln[j];
#pragma unroll
    for (int o = 1; o < 16; o <<= 1) m = fmaxf(m, __shfl_xor(m, o));
    float c = s_ln[j] * exp2f((m_ln[j] - m) * C2);
#pragma unroll
    for (int o = 1; o < 16; o <<= 1) c += __shfl_xor(c, o);
    mC[j] = m * C2 + __log2f(c);
  }

  // ---- pass 2 prologue: stage K,V tile 0, issue tile 1 ----
  gk0 = *(const uint4*)(kbase + (size_t)sr0 * ND + sc0 * 8);
  gv0 = *(const uint4*)(vbase + (size_t)sr0 * 4 * NN + sc0 * 8);
  *(uint4*)((char*)Kl[0] + d0) = gk0;
  *(uint4*)((char*)Vl[0] + d0) = gv0;
  gk0 = *(const uint4*)(kbase + (size_t)(64 + sr0) * ND + sc0 * 8);
  gv0 = *(const uint4*)(vbase + (size_t)sr0 * 4 * NN + 64 + sc0 * 8);
  bar_lds();

  // ---- pass 2: recompute S, write attn once, PV; one LDS barrier per tile ----
  f32x4 acc[4] = {};
  const int prow = w * 16 + lr;
  char* plb = (char*)Pl;
  for (int t = 0; t < 32; ++t) {
    int kb = t & 1;
    if (t < 31) {
      *(uint4*)((char*)Kl[kb ^ 1] + d0) = gk0;
      *(uint4*)((char*)Vl[kb ^ 1] + d0) = gv0;
    }
    if (t < 30) {
      gk0 = *(const uint4*)(kbase + ((size_t)(t + 2) * 64 + sr0) * ND + sc0 * 8);
      gv0 = *(const uint4*)(vbase + (size_t)sr0 * 4 * NN + (t + 2) * 64 + sc0 * 8);
    }
    f32x4 sa[4] = {};
#pragma unroll
    for (int ks = 0; ks < 2; ++ks) {
      bf16x8 aqk = ks ? aq1 : aq0;
#pragma unroll
      for (int fc = 0; fc < 4; ++fc)
        sa[fc] = __builtin_amdgcn_mfma_f32_16x16x32_bf16(aqk, ldtile(Kl[kb], lr, lg, fc, ks), sa[fc], 0, 0, 0);
    }
    // normalized P -> LDS (bf16, swizzled); norm folded into exponent
#pragma unroll
    for (int fc = 0; fc < 4; ++fc)
#pragma unroll
      for (int j = 0; j < 4; ++j) {
        int row = w * 16 + lg * 4 + j;
        float p = exp2f(fmaf(sa[fc][j], C2, -mC[j]));
        int byte = (row << 7) + ((fc * 16 + lr) << 1);
        byte ^= (row & 7) << 4;
        *(ushort*)(plb + byte) = f2bf(p);
      }
    // attn store: vectorized f32x4 NT from the LDS P tile (wave-local slab)
    float* abase = attn + ((size_t)z * NN + r0) * NN + t * 64;
#pragma unroll
    for (int k = 0; k < 4; ++k) {
      int row = w * 16 + lg + k * 4;
      int byte = (row << 7) + (lr << 3);
      byte ^= (row & 7) << 4;
      const ushort* pq = (const ushort*)(plb + byte);
      f32x4 vv = { bf2f(pq[0]), bf2f(pq[1]), bf2f(pq[2]), bf2f(pq[3]) };
      __builtin_nontemporal_store(vv, (f32x4*)(abase + (size_t)row * NN + lr * 4));
    }
    // PV MFMA from LDS P and V
#pragma unroll
    for (int ks = 0; ks < 2; ++ks) {
      int abyte = (prow << 7) + ks * 64 + lg * 16;
      abyte ^= (prow & 7) << 4;
      bf16x8 ap = *(const bf16x8*)(plb + abyte);
#pragma unroll
      for (int fc = 0; fc < 4; ++fc)
        acc[fc] = __builtin_amdgcn_mfma_f32_16x16x32_bf16(ap, ldtile(Vl[kb], lr, lg, fc, ks), acc[fc], 0, 0, 0);
    }
    bar_lds();
  }
  // epilogue: xT[b][n][h*64+d]
#pragma unroll
  for (int fc = 0; fc < 4; ++fc)
#pragma unroll
    for (int j = 0; j < 4; ++j) {
      int n = r0 + w * 16 + lg * 4 + j;
      xT[((size_t)b * NN + n) * NC + h * 64 + fc * 16 + lr] = f2bf(acc[fc][j]);
    }
}

// ---------------- generic MFMA GEMM: D[r][c] = sum_k A[r][k]*B[c][k] ----------------

enum GemmMode { M_PROJ = 0, M_WM, M_W1, M_W2 };

template <int MODE>
__global__ __launch_bounds__(256) void k_gemm(
    const ushort* __restrict__ A, const ushort* __restrict__ Bm,
    const float* __restrict__ Fa, const float* __restrict__ Fb, const float* __restrict__ Fc,
    const float* __restrict__ b0, const float* __restrict__ b1v, const float* __restrict__ b2v,
    const float4* __restrict__ aff, float* __restrict__ stats,
    float* __restrict__ outf, ushort* __restrict__ outb, ushort* __restrict__ outb2) {
  constexpr int BR = (MODE == M_WM || MODE == M_W1) ? 64 : 128;
  constexpr int BC = (MODE == M_W1) ? 256 : (MODE == M_W2) ? 64 : 128;
  constexpr int KT = (MODE == M_PROJ || MODE == M_WM) ? 256 : 512;
  constexpr int FR = BR / 32;
  constexpr int FC = BC / 32;
  constexpr int LDL = 72;

  __shared__ ushort ldsU[BR * LDL + BC * LDL];
  ushort* ldsA = ldsU;
  ushort* ldsB = ldsU + BR * LDL;

  const int tid = threadIdx.x;
  const int lane = tid & 63, wave = tid >> 6;
  const int wr = (wave >> 1) * (FR * 16), wc = (wave & 1) * (FC * 16);
  const int lr = lane & 15, lg = lane >> 4, lk = lg * 8;
  const int c0 = blockIdx.x * BC, r0 = blockIdx.y * BR;
  const int op = (MODE == M_PROJ) ? (int)(blockIdx.z >> 3) : 0;
  const size_t z = (MODE == M_PROJ) ? (blockIdx.z & 7) : blockIdx.z;

  // stage [ROWS rows][64 k] bf16 tile from f32 src laid out [k][row] (stride NN)
  auto stage_t = [&](ushort* dst, const float* src, int ROWS) {
    int n = tid & (ROWS - 1), cgb = tid / ROWS;
    int gpp = 256 / ROWS;
    for (int u = 0; u < 8 / gpp; ++u) {
      int cg = cgb + u * gpp;
      union { ushort us[8]; uint4 v; } pk;
#pragma unroll
      for (int e = 0; e < 8; ++e)
        pk.us[e] = f2bf(src[(size_t)(cg * 8 + e) * NN + n]);
      *(uint4*)&dst[n * LDL + cg * 8] = pk.v;
    }
  };

  f32x4 acc[FR][FC] = {};

  for (int kk = 0; kk < KT; kk += 64) {
    // ---- stage A ----
    if constexpr (MODE == M_W1) {
      if (kk < NC) {
        const ushort* src = A + (z * NN + r0) * (size_t)NC + kk;
#pragma unroll
        for (int i = 0; i < BR / 32; ++i) {
          int off = (tid + i * 256) * 8, row = off >> 6, k = off & 63;
          *(uint4*)&ldsA[row * LDL + k] = *(const uint4*)(src + (size_t)row * NC + k);
        }
      } else {
        stage_t(ldsA, Fa + ((size_t)z * NC + (kk - NC)) * NN + r0, BR);
      }
    } else {
      const ushort* src; int ld;
      if constexpr (MODE == M_PROJ)        { src = A + (size_t)op * NC * NC + (size_t)r0 * NC + kk; ld = NC; }
      else if constexpr (MODE == M_WM)     { src = A + (z * NN + r0) * (size_t)NC + kk; ld = NC; }
      else                                  { src = A + (size_t)r0 * NC2 + kk; ld = NC2; }   // M_W2
#pragma unroll
      for (int i = 0; i < BR / 32; ++i) {
        int off = (tid + i * 256) * 8, row = off >> 6, k = off & 63;
        *(uint4*)&ldsA[row * LDL + k] = *(const uint4*)(src + (size_t)row * ld + k);
      }
    }
    // ---- stage B ----
    if constexpr (MODE == M_PROJ) {
      const float* Fsel = op == 0 ? Fa : op == 1 ? Fb : Fc;
      stage_t(ldsB, Fsel + ((size_t)z * NC + kk) * NN + c0, BC);
    } else if constexpr (MODE == M_W2) {
      const ushort* src = Bm + (z * NN + c0) * (size_t)NC2 + kk;
#pragma unroll
      for (int i = 0; i < BC / 32; ++i) {
        int off = (tid + i * 256) * 8, row = off >> 6, k = off & 63;
        union { ushort u[8]; uint4 v; } t, o;
        t.v = *(const uint4*)(src + (size_t)row * NC2 + k);
#pragma unroll
        for (int e = 0; e < 8; ++e) {
          float4 pr = aff[kk + k + e];
          float y = (bf2f(t.u[e]) - pr.x) * pr.y + pr.z;
          y = y > 0.f ? y : 0.2f * y;
          o.u[e] = f2bf(y);
        }
        *(uint4*)&ldsB[row * LDL + k] = o.v;
      }
    } else {
      const ushort* src; int ld;
      if constexpr (MODE == M_WM)          { src = Bm + (size_t)c0 * NC + kk; ld = NC; }
      else                                  { src = Bm + (size_t)c0 * NC2 + kk; ld = NC2; }  // M_W1
#pragma unroll
      for (int i = 0; i < BC / 32; ++i) {
        int off = (tid + i * 256) * 8, row = off >> 6, k = off & 63;
        *(uint4*)&ldsB[row * LDL + k] = *(const uint4*)(src + (size_t)row * ld + k);
      }
    }
    __syncthreads();
#pragma unroll
    for (int ks = 0; ks < 2; ++ks) {
      bf16x8 afr[FR], bfr[FC];
#pragma unroll
      for (int fr = 0; fr < FR; ++fr)
        afr[fr] = *(const bf16x8*)&ldsA[(wr + fr * 16 + lr) * LDL + ks * 32 + lk];
#pragma unroll
      for (int fc = 0; fc < FC; ++fc)
        bfr[fc] = *(const bf16x8*)&ldsB[(wc + fc * 16 + lr) * LDL + ks * 32 + lk];
#pragma unroll
      for (int fr = 0; fr < FR; ++fr)
#pragma unroll
        for (int fc = 0; fc < FC; ++fc)
          acc[fr][fc] = __builtin_amdgcn_mfma_f32_16x16x32_bf16(afr[fr], bfr[fc], acc[fr][fc], 0, 0, 0);
    }
    __syncthreads();
  }

  // ---- epilogues ----
  if constexpr (MODE == M_PROJ) {
    if (op < 2) {
      // transpose via LDS (reuse staging space), coalesced write to qt/kt [z][n][d]
      const float* bb = op == 0 ? b0 : b1v;
      char* tb = (char*)ldsU;
#pragma unroll
      for (int fr = 0; fr < FR; ++fr)
#pragma unroll
        for (int fc = 0; fc < FC; ++fc) {
          int n_l = wc + fc * 16 + lr;
          int rb = wr + fr * 16 + lg * 4;
          union { ushort u[4]; uint2 v; } pk;
#pragma unroll
          for (int j = 0; j < 4; ++j) {
            int r = r0 + rb + j;
            pk.u[j] = f2bf(acc[fr][fc][j] + bb[((r & 63) << 2) | (r >> 6)]);
          }
          int byte = n_l * 256 + rb * 2;
          byte ^= (n_l & 7) << 4;
          *(uint2*)(tb + byte) = pk.v;
        }
      __syncthreads();
      ushort* dst = outb + (size_t)op * TND;
#pragma unroll
      for (int hh = 0; hh < 2; ++hh) {
        size_t zz = z * 4 + (r0 >> 6) + hh;
#pragma unroll
        for (int u = 0; u < 4; ++u) {
          int seg = u * 256 + tid;
          int n_l = seg >> 3, dd = (seg & 7) * 8;
          int byte = n_l * 256 + (hh * 64 + dd) * 2;
          byte ^= (n_l & 7) << 4;
          uint4 v = *(const uint4*)(tb + byte);
          *(uint4*)(dst + (zz * NN + c0 + n_l) * (size_t)ND + dd) = v;
        }
      }
    } else {
#pragma unroll
      for (int fr = 0; fr < FR; ++fr)
#pragma unroll
        for (int fc = 0; fc < FC; ++fc)
#pragma unroll
          for (int j = 0; j < 4; ++j) {
            int r = r0 + wr + fr * 16 + lg * 4 + j;
            int c = c0 + wc + fc * 16 + lr;
            outb2[(z * NC + r) * (size_t)NN + c] = f2bf(acc[fr][fc][j] + b2v[r]);
          }
    }
    return;
  }

  float sfc[FC], qfc[FC];
#pragma unroll
  for (int fc = 0; fc < FC; ++fc) { sfc[fc] = 0.f; qfc[fc] = 0.f; }
#pragma unroll
  for (int fr = 0; fr < FR; ++fr)
#pragma unroll
    for (int fc = 0; fc < FC; ++fc)
#pragma unroll
      for (int j = 0; j < 4; ++j) {
        int r = r0 + wr + fr * 16 + lg * 4 + j;
        int c = c0 + wc + fc * 16 + lr;
        float v = acc[fr][fc][j];
        if constexpr (MODE == M_WM) {
          v += b0[c];
          outb[(z * NN + r) * (size_t)NC + c] = f2bf(v);
        } else if constexpr (MODE == M_W1) {
          v += b0[c];
          outb[(z * NN + r) * (size_t)NC2 + c] = f2bf(v);
          sfc[fc] += v; qfc[fc] += v * v;
        } else {  // M_W2
          v += b0[r];
          outf[(z * NC + r) * (size_t)NN + c] = v;
        }
      }
  if constexpr (MODE == M_W1) {
#pragma unroll
    for (int fc = 0; fc < FC; ++fc) {
      float s1 = sfc[fc], s2 = qfc[fc];
      s1 += __shfl_xor(s1, 16); s1 += __shfl_xor(s1, 32);
      s2 += __shfl_xor(s2, 16); s2 += __shfl_xor(s2, 32);
      if (lane < 16) {
        int ch = c0 + wc + fc * 16 + lane;
        atomicAdd(&stats[ch * 2],     s1);
        atomicAdd(&stats[ch * 2 + 1], s2);
      }
    }
  }
}

// ---------------- launch ----------------

extern "C" void kernel_launch(void* const* d_in, const int* in_sizes, int n_in,
                              void* d_out, int out_size, void* d_ws, size_t ws_size,
                              hipStream_t stream) {
  const float* iq    = (const float*)d_in[0];
  const float* keyi  = (const float*)d_in[1];
  const float* vali  = (const float*)d_in[2];
  const float* Wq = (const float*)d_in[3];  const float* bq = (const float*)d_in[4];
  const float* Wk = (const float*)d_in[5];  const float* bk = (const float*)d_in[6];
  const float* Wv = (const float*)d_in[7];  const float* bv = (const float*)d_in[8];
  const float* Wm = (const float*)d_in[9];  const float* bm = (const float*)d_in[10];
  const float* W1 = (const float*)d_in[11]; const float* b1 = (const float*)d_in[12];
  const float* gamma = (const float*)d_in[13]; const float* beta = (const float*)d_in[14];
  const float* W2 = (const float*)d_in[15]; const float* b2 = (const float*)d_in[16];

  float* out  = (float*)d_out;
  float* attn = out + (size_t)NB * NC * NN;   // [B,H,N,N] f32

  uint8_t* cur = (uint8_t*)d_ws;
  auto alloc = [&](size_t bytes) { uint8_t* p = cur; cur += (bytes + 255) & ~(size_t)255; return p; };
  ushort* wqkv  = (ushort*)alloc((size_t)NC * NC * 2 * 3);   // q(perm)|k(perm)|v
  ushort* wm_b  = (ushort*)alloc((size_t)NC * NC * 2);
  ushort* w1_b  = (ushort*)alloc((size_t)NC2 * NC2 * 2);
  ushort* w2_b  = (ushort*)alloc((size_t)NC * NC2 * 2);
  ushort* qtkt  = (ushort*)alloc(TND * 2 * 2);  // qt|kt [(b h)][n][d]
  ushort* v_nat = (ushort*)alloc(TND * 2);      // [b][c_out][n]
  ushort* xT    = (ushort*)alloc(TND * 2);      // attn@V, [b][n][h*64+d]
  ushort* xmT   = (ushort*)alloc(TND * 2);      // merge out^T [b][n][co]
  ushort* hT    = (ushort*)alloc((size_t)NB * NN * NC2 * 2);
  float*  stats = (float*)alloc(NC2 * 2 * 4);
  float4* aff   = (float4*)alloc(NC2 * 16);
  ushort* kt    = qtkt + TND;

  (void)hipMemsetAsync(stats, 0, NC2 * 2 * 4, stream);

  k_cast_all<<<dim3(2560), 256, 0, stream>>>(Wq, Wk, Wv, Wm, W1, W2, wqkv, wm_b, w1_b, w2_b);

  k_gemm<M_PROJ><<<dim3(16, 2, 24), 256, 0, stream>>>(
      wqkv, nullptr, iq, keyi, vali, bq, bk, bv, nullptr, nullptr, nullptr, qtkt, v_nat);

  k_attn<<<dim3(512), 512, 0, stream>>>(qtkt, kt, v_nat, attn, xT);

  k_gemm<M_WM><<<dim3(2, 32, 8), 256, 0, stream>>>(
      xT, wm_b, nullptr, nullptr, nullptr, bm, nullptr, nullptr, nullptr, nullptr, nullptr, xmT, nullptr);

  k_gemm<M_W1><<<dim3(2, 32, 8), 256, 0, stream>>>(
      xmT, w1_b, iq, nullptr, nullptr, b1, nullptr, nullptr, nullptr, stats, nullptr, hT, nullptr);

  k_bn_finalize<<<dim3(2), 256, 0, stream>>>(stats, gamma, beta, aff);

  k_gemm<M_W2><<<dim3(32, 2, 8), 256, 0, stream>>>(
      w2_b, hT, nullptr, nullptr, nullptr, b2, nullptr, nullptr, aff, nullptr, out, nullptr, nullptr);
}